// Round 11
// baseline (60.597 us; speedup 1.0000x reference)
//
#include <hip/hip_runtime.h>

typedef __attribute__((ext_vector_type(4))) float v4f;
typedef __attribute__((ext_vector_type(8))) short short8;
typedef unsigned short u16;
typedef unsigned int u32;
typedef __attribute__((ext_vector_type(2))) unsigned int u32x2;
typedef __attribute__((ext_vector_type(4))) unsigned int u32x4;
typedef __attribute__((ext_vector_type(8))) unsigned short u16x8;

#define CDIM 256
#define NB 8
#define NN 4096
#define MM 4096

static __device__ __forceinline__ u16 f2bf(float f) {
  unsigned u = __float_as_uint(f);
  u = (u + 0x7fffu + ((u >> 16) & 1u)) >> 16;  // RNE
  return (u16)u;
}
static __device__ __forceinline__ float bf2f(u16 h) {
  return __uint_as_float(((unsigned)h) << 16);
}
static __device__ __forceinline__ u32 pack2(float a, float b) {
  return (u32)f2bf(a) | ((u32)f2bf(b) << 16);
}

// swizzled index into a [C c][32 m] u16 tile (conflict-managed, proven in R9)
static __device__ __forceinline__ int sidx32(int c, int m) {
  return (c * 32 + m) ^ (((c >> 1) & 7) << 3);
}

// 4x4 bf16 transpose among lanes {l, l^16, l^32, l^48} (proven R7/R9).
static __device__ __forceinline__ u32x2 xpose4(u32 A, u32 B, int hi) {
  u32 tA = (u32)__shfl_xor((int)A, 32);
  u32 tB = (u32)__shfl_xor((int)B, 32);
  u32 U = (hi < 2) ? A : tB;
  u32 V = (hi < 2) ? tA : B;
  u32 tU = (u32)__shfl_xor((int)U, 16);
  u32 tV = (u32)__shfl_xor((int)V, 16);
  u32 Up, Vp;
  if ((hi & 1) == 0) {
    Up = (U & 0xffffu) | (tU << 16);
    Vp = (V & 0xffffu) | (tV << 16);
  } else {
    Up = (tU >> 16) | (U & 0xffff0000u);
    Vp = (tV >> 16) | (V & 0xffff0000u);
  }
  return (u32x2){Up, Vp};
}

#define BARRIER() do { \
  asm volatile("s_waitcnt lgkmcnt(0)" ::: "memory"); \
  __builtin_amdgcn_s_barrier(); \
  __builtin_amdgcn_sched_barrier(0); \
} while (0)

// ---------------- K1: kv partials = v^T @ (k/||k||), split-K + d-half split ----------------
// grid (splits, NB, 2): block h owns d-columns [h*128, h*128+128) -> 512 blocks = 2/CU.
// Register-order partial: slice [(s*NB+b)] = [2 h][32 reg32][512 T] u32 (dense stores).
__global__ __launch_bounds__(512) void kv_kernel(const float* __restrict__ key,
                                                 const float* __restrict__ value,
                                                 u16* __restrict__ partial, int KC) {
  __shared__ __align__(16) u16 KL[2][256 * 32];  // 16 KB per buf
  __shared__ __align__(16) u16 VL[2][128 * 32];  // 8 KB per buf
  int t = threadIdx.x;
  int b = blockIdx.y, s = blockIdx.x, h = blockIdx.z;
  int w = t >> 6, lane = t & 63, lo = lane & 15, hi = lane >> 4;

  const float* kbase = key + ((size_t)b * MM + (size_t)s * KC) * CDIM;
  const float* vbase = value + ((size_t)b * MM + (size_t)s * KC) * CDIM + h * 128;

  v4f acc[2][8];
  #pragma unroll
  for (int i = 0; i < 2; i++)
    #pragma unroll
    for (int d = 0; d < 8; d++) acc[i][d] = (v4f){0.f, 0.f, 0.f, 0.f};

  v4f kqA[4], vqA[2], kqB[4], vqB[2];  // two named staging sets (rule #20)

  auto LOADS = [&](int sc, v4f (&kq)[4], v4f (&vq)[2]) {
    int row = sc * 32 + w * 4 + hi;  // wave w stages rows w*4..w*4+3
    const float* kr = kbase + (size_t)row * CDIM + lo * 4;
    const float* vr = vbase + (size_t)row * CDIM + lo * 4;
    #pragma unroll
    for (int qt = 0; qt < 4; ++qt) kq[qt] = *(const v4f*)(kr + qt * 64);
    #pragma unroll
    for (int qt = 0; qt < 2; ++qt) vq[qt] = *(const v4f*)(vr + qt * 64);
  };
  auto STORE = [&](int bufi, v4f (&kq)[4], v4f (&vq)[2]) {
    int m0 = w * 4;
    float ss = 0.f;
    #pragma unroll
    for (int qt = 0; qt < 4; ++qt)
      ss += kq[qt][0]*kq[qt][0] + kq[qt][1]*kq[qt][1] + kq[qt][2]*kq[qt][2] + kq[qt][3]*kq[qt][3];
    #pragma unroll
    for (int m = 1; m < 16; m <<= 1) ss += __shfl_xor(ss, m);  // row spans 16 lanes
    float sc_ = 1.0f / fmaxf(sqrtf(ss), 1e-12f);
    #pragma unroll
    for (int qt = 0; qt < 4; ++qt) {
      int c = qt * 64 + lo * 4 + hi;
      u32x2 ko = xpose4(pack2(kq[qt][0] * sc_, kq[qt][1] * sc_),
                        pack2(kq[qt][2] * sc_, kq[qt][3] * sc_), hi);
      *(u32x2*)&KL[bufi][sidx32(c, m0)] = ko;
    }
    #pragma unroll
    for (int qt = 0; qt < 2; ++qt) {
      int c = qt * 64 + lo * 4 + hi;  // local d-column
      u32x2 vo = xpose4(pack2(vq[qt][0], vq[qt][1]),
                        pack2(vq[qt][2], vq[qt][3]), hi);
      *(u32x2*)&VL[bufi][sidx32(c, m0)] = vo;
    }
  };
  auto MF = [&](const u16* KB, const u16* VB) {
    int acol = hi * 8;
    int r0 = w * 32 + lo, r1 = w * 32 + 16 + lo;
    short8 a0 = *(const short8*)&KB[(r0 * 32 + acol) ^ (((r0 >> 1) & 7) << 3)];
    short8 a1 = *(const short8*)&KB[(r1 * 32 + acol) ^ (((r1 >> 1) & 7) << 3)];
    #pragma unroll
    for (int dt = 0; dt < 8; ++dt) {
      int drow = dt * 16 + lo;
      short8 bb = *(const short8*)&VB[(drow * 32 + acol) ^ (((drow >> 1) & 7) << 3)];
      acc[0][dt] = __builtin_amdgcn_mfma_f32_16x16x32_bf16(bb, a0, acc[0][dt], 0, 0, 0);
      acc[1][dt] = __builtin_amdgcn_mfma_f32_16x16x32_bf16(bb, a1, acc[1][dt], 0, 0, 0);
    }
  };

  // ---- 2-deep pipeline over 32-row subtiles (nsc = KC/32 >= 4) ----
  int nsc = KC >> 5;
  LOADS(0, kqA, vqA);
  LOADS(1, kqB, vqB);
  STORE(0, kqA, vqA);
  BARRIER();
  for (int i = 0; i < nsc; i += 2) {
    if (i + 2 < nsc) LOADS(i + 2, kqA, vqA);
    MF(KL[0], VL[0]);
    if (i + 1 < nsc) {
      STORE(1, kqB, vqB);
      BARRIER();
      if (i + 3 < nsc) LOADS(i + 3, kqB, vqB);
      MF(KL[1], VL[1]);
      if (i + 2 < nsc) {
        STORE(0, kqA, vqA);
        BARRIER();
      }
    }
  }

  // epilogue: register-order partial, 32 dense 256B wave-stores.
  // slice layout: u32 [2 h][32 reg32][512 T]; reg32 = i*16 + dt*2 + p,
  // value = pack2(acc[i][dt][2p], acc[i][dt][2p+1]).
  u32* p32 = (u32*)partial;
  size_t sbase = (((size_t)(s * NB + b)) * 2 + h) * 16384;
  #pragma unroll
  for (int i = 0; i < 2; i++)
    #pragma unroll
    for (int dt = 0; dt < 8; ++dt)
      #pragma unroll
      for (int p = 0; p < 2; ++p) {
        int reg32 = i * 16 + dt * 2 + p;
        p32[sbase + reg32 * 512 + t] = pack2(acc[i][dt][2 * p], acc[i][dt][2 * p + 1]);
      }
}

// ---------------- K2: reduce register-order partials, scale 1/N, write kvT[d][c] bf16 ----------------
__global__ __launch_bounds__(256) void red_kernel(const u16* __restrict__ partial,
                                                  u16* __restrict__ kvT, int splits) {
  const u32* p32 = (const u32*)partial;
  int j = blockIdx.x * 256 + threadIdx.x;   // 0..65535
  int b = j >> 13;
  int F = (j & 8191) * 4;                   // u32 offset within slice [0, 32768)
  int h = F >> 14, reg32 = (F >> 9) & 31, T0 = F & 511;
  int i = reg32 >> 4, dt = (reg32 >> 1) & 7, p = reg32 & 1;
  const float inv = 1.0f / 4096.0f;
  float sum[8] = {0.f, 0.f, 0.f, 0.f, 0.f, 0.f, 0.f, 0.f};
  size_t off = (size_t)h * 16384 + (size_t)reg32 * 512 + T0;
  for (int s2 = 0; s2 < splits; ++s2) {
    u32x4 v = *(const u32x4*)&p32[((size_t)(s2 * NB + b)) * 32768 + off];
    #pragma unroll
    for (int x = 0; x < 4; ++x) {
      sum[2 * x]     += bf2f((u16)(v[x] & 0xffffu));
      sum[2 * x + 1] += bf2f((u16)(v[x] >> 16));
    }
  }
  #pragma unroll
  for (int tt = 0; tt < 4; ++tt) {
    int T = T0 + tt;
    int w = T >> 6, lane2 = T & 63, lo = lane2 & 15, hi2 = lane2 >> 4;
    int c = w * 32 + i * 16 + lo;
    int d = h * 128 + dt * 16 + hi2 * 4 + 2 * p;
    kvT[((size_t)(b * 256 + d)) * 256 + c]     = f2bf(sum[2 * tt] * inv);
    kvT[((size_t)(b * 256 + d + 1)) * 256 + c] = f2bf(sum[2 * tt + 1] * inv);
  }
}

// ---------------- K3: out = normalize(q) @ kv (unchanged, proven) ----------------
__global__ __launch_bounds__(512) void ctx_kernel(const float* __restrict__ query,
                                                  const u16* __restrict__ kvT,
                                                  float* __restrict__ out) {
  __shared__ __align__(16) u16 qn[2][16 * 256];
  int t = threadIdx.x;
  int b = blockIdx.y;
  int tile0 = blockIdx.x * 4;
  int w = t >> 6, lane = t & 63, lo = lane & 15, hi = lane >> 4;
  int row = t >> 5, l32 = t & 31;
  const float* qbase = query + (size_t)b * NN * CDIM + (size_t)row * CDIM + l32 * 8;

  const float* qr0 = qbase + (size_t)(tile0 * 16) * CDIM;
  v4f x0 = *(const v4f*)qr0;
  v4f x1 = *(const v4f*)(qr0 + 4);

  const u16* kvb = kvT + ((size_t)b << 16);
  short8 Bf[2][8];
  #pragma unroll
  for (int i = 0; i < 2; i++) {
    int dr = (2 * w + i) * 16 + lo;
    #pragma unroll
    for (int kc = 0; kc < 8; kc++)
      Bf[i][kc] = *(const short8*)&kvb[(size_t)dr * 256 + kc * 32 + 8 * hi];
  }

  {
    float ss = x0[0]*x0[0] + x0[1]*x0[1] + x0[2]*x0[2] + x0[3]*x0[3]
             + x1[0]*x1[0] + x1[1]*x1[1] + x1[2]*x1[2] + x1[3]*x1[3];
    #pragma unroll
    for (int m = 1; m < 32; m <<= 1) ss += __shfl_xor(ss, m);
    float sc = 1.0f / fmaxf(sqrtf(ss), 1e-12f);
    u16x8 qb;
    qb[0] = f2bf(x0[0] * sc); qb[1] = f2bf(x0[1] * sc);
    qb[2] = f2bf(x0[2] * sc); qb[3] = f2bf(x0[3] * sc);
    qb[4] = f2bf(x1[0] * sc); qb[5] = f2bf(x1[1] * sc);
    qb[6] = f2bf(x1[2] * sc); qb[7] = f2bf(x1[3] * sc);
    *(u16x8*)&qn[0][(row * 256 + l32 * 8) ^ ((row & 7) << 3)] = qb;
  }

  int cur = 0;
  #pragma unroll
  for (int nt = 0; nt < 4; ++nt) {
    v4f p0, p1;
    if (nt < 3) {
      const float* qr = qbase + (size_t)((tile0 + nt + 1) * 16) * CDIM;
      p0 = *(const v4f*)qr;
      p1 = *(const v4f*)(qr + 4);
    }
    __syncthreads();
    short8 Af[8];
    #pragma unroll
    for (int kc = 0; kc < 8; kc++)
      Af[kc] = *(const short8*)&qn[cur][(lo * 256 + kc * 32 + 8 * hi) ^ ((lo & 7) << 3)];
    v4f acc0 = (v4f){0.f, 0.f, 0.f, 0.f};
    v4f acc1 = (v4f){0.f, 0.f, 0.f, 0.f};
    #pragma unroll
    for (int kc = 0; kc < 8; kc++) {
      acc0 = __builtin_amdgcn_mfma_f32_16x16x32_bf16(Af[kc], Bf[0][kc], acc0, 0, 0, 0);
      acc1 = __builtin_amdgcn_mfma_f32_16x16x32_bf16(Af[kc], Bf[1][kc], acc1, 0, 0, 0);
    }
    int n0 = (tile0 + nt) * 16;
    #pragma unroll
    for (int r = 0; r < 4; r++) {
      size_t ro = (size_t)(b * NN + n0 + 4 * hi + r) * CDIM;
      out[ro + (2 * w) * 16 + lo] = acc0[r];
      out[ro + (2 * w + 1) * 16 + lo] = acc1[r];
    }
    if (nt < 3) {
      float ss = p0[0]*p0[0] + p0[1]*p0[1] + p0[2]*p0[2] + p0[3]*p0[3]
               + p1[0]*p1[0] + p1[1]*p1[1] + p1[2]*p1[2] + p1[3]*p1[3];
      #pragma unroll
      for (int m = 1; m < 32; m <<= 1) ss += __shfl_xor(ss, m);
      float sc = 1.0f / fmaxf(sqrtf(ss), 1e-12f);
      u16x8 qb;
      qb[0] = f2bf(p0[0] * sc); qb[1] = f2bf(p0[1] * sc);
      qb[2] = f2bf(p0[2] * sc); qb[3] = f2bf(p0[3] * sc);
      qb[4] = f2bf(p1[0] * sc); qb[5] = f2bf(p1[1] * sc);
      qb[6] = f2bf(p1[2] * sc); qb[7] = f2bf(p1[3] * sc);
      *(u16x8*)&qn[cur ^ 1][(row * 256 + l32 * 8) ^ ((row & 7) << 3)] = qb;
      cur ^= 1;
    }
  }
}

extern "C" void kernel_launch(void* const* d_in, const int* in_sizes, int n_in,
                              void* d_out, int out_size, void* d_ws, size_t ws_size,
                              hipStream_t stream) {
  const float* q = (const float*)d_in[0];
  const float* k = (const float*)d_in[1];
  const float* v = (const float*)d_in[2];
  float* out = (float*)d_out;

  // ws layout: [partial: splits*8*256*256 bf16][kvT: 8*256*256 bf16]
  int splits = 32;
  while (splits > 2) {
    size_t need = ((size_t)splits + 1ull) * 1048576ull;
    if (need <= ws_size) break;
    splits >>= 1;
  }
  u16* partial = (u16*)d_ws;
  u16* kvT = (u16*)((char*)d_ws + (size_t)splits * 1048576ull);

  kv_kernel<<<dim3(splits, NB, 2), dim3(512), 0, stream>>>(k, v, partial, MM / splits);
  red_kernel<<<dim3(256), dim3(256), 0, stream>>>(partial, kvT, splits);
  ctx_kernel<<<dim3(64, NB), dim3(512), 0, stream>>>(q, kvT, out);
}

// Round 12
// 56.949 us; speedup vs baseline: 1.0641x; 1.0641x over previous
//
#include <hip/hip_runtime.h>

typedef __attribute__((ext_vector_type(4))) float v4f;
typedef __attribute__((ext_vector_type(8))) short short8;
typedef unsigned short u16;
typedef unsigned int u32;
typedef __attribute__((ext_vector_type(2))) unsigned int u32x2;
typedef __attribute__((ext_vector_type(8))) unsigned short u16x8;

#define CDIM 256
#define NB 8
#define NN 4096
#define MM 4096

static __device__ __forceinline__ u16 f2bf(float f) {
  unsigned u = __float_as_uint(f);
  u = (u + 0x7fffu + ((u >> 16) & 1u)) >> 16;  // RNE
  return (u16)u;
}
static __device__ __forceinline__ float bf2f(u16 h) {
  return __uint_as_float(((unsigned)h) << 16);
}
static __device__ __forceinline__ u32 pack2(float a, float b) {
  return (u32)f2bf(a) | ((u32)f2bf(b) << 16);
}

// swizzled index into a [256 c][32 m] u16 tile (proven R9)
static __device__ __forceinline__ int sidx32(int c, int m) {
  return (c * 32 + m) ^ (((c >> 1) & 7) << 3);
}

// 4x4 bf16 transpose among lanes {l, l^16, l^32, l^48} (proven R7/R9).
static __device__ __forceinline__ u32x2 xpose4(u32 A, u32 B, int hi) {
  u32 tA = (u32)__shfl_xor((int)A, 32);
  u32 tB = (u32)__shfl_xor((int)B, 32);
  u32 U = (hi < 2) ? A : tB;
  u32 V = (hi < 2) ? tA : B;
  u32 tU = (u32)__shfl_xor((int)U, 16);
  u32 tV = (u32)__shfl_xor((int)V, 16);
  u32 Up, Vp;
  if ((hi & 1) == 0) {
    Up = (U & 0xffffu) | (tU << 16);
    Vp = (V & 0xffffu) | (tV << 16);
  } else {
    Up = (tU >> 16) | (U & 0xffff0000u);
    Vp = (tV >> 16) | (V & 0xffff0000u);
  }
  return (u32x2){Up, Vp};
}

#define BARRIER() do { \
  asm volatile("s_waitcnt lgkmcnt(0)" ::: "memory"); \
  __builtin_amdgcn_s_barrier(); \
  __builtin_amdgcn_sched_barrier(0); \
} while (0)

// pin: nothing (esp. the just-issued global loads) may cross this point
#define PIN() __builtin_amdgcn_sched_barrier(0)

// ---------------- K1: kv partials = v^T @ (k/||k||), split-K, output [d][c] ----------------
// 2-deep pipelined 32-row subtiles. launch_bounds(512,1) frees the VGPR budget so
// both staging sets stay live; sched_barrier(0) after LOADS pins issue order
// (R9/R10 compiled to VGPR=64 with loads sunk to their consumers -> no pipeline).
__global__ __launch_bounds__(512, 1) void kv_kernel(const float* __restrict__ key,
                                                    const float* __restrict__ value,
                                                    u16* __restrict__ partial, int KC) {
  __shared__ __align__(16) u16 KL[2][256 * 32];  // 16 KB per buf
  __shared__ __align__(16) u16 VL[2][256 * 32];
  int t = threadIdx.x;
  int b = blockIdx.y, s = blockIdx.x;
  int w = t >> 6, lane = t & 63, lo = lane & 15, hi = lane >> 4;

  const float* kbase = key + ((size_t)b * MM + (size_t)s * KC) * CDIM;
  const float* vbase = value + ((size_t)b * MM + (size_t)s * KC) * CDIM;

  v4f acc[2][16];
  #pragma unroll
  for (int i = 0; i < 2; i++)
    #pragma unroll
    for (int d = 0; d < 16; d++) acc[i][d] = (v4f){0.f, 0.f, 0.f, 0.f};

  v4f kqA[4], vqA[4], kqB[4], vqB[4];  // two named staging sets (rule #20)

  auto LOADS = [&](int sc, v4f (&kq)[4], v4f (&vq)[4]) {
    int row = sc * 32 + w * 4 + hi;  // wave w stages rows w*4..w*4+3
    const float* kr = kbase + (size_t)row * CDIM + lo * 4;
    const float* vr = vbase + (size_t)row * CDIM + lo * 4;
    #pragma unroll
    for (int qt = 0; qt < 4; ++qt) {
      kq[qt] = *(const v4f*)(kr + qt * 64);
      vq[qt] = *(const v4f*)(vr + qt * 64);
    }
  };
  auto STORE = [&](int bufi, v4f (&kq)[4], v4f (&vq)[4]) {
    int m0 = w * 4;
    float ss = 0.f;
    #pragma unroll
    for (int qt = 0; qt < 4; ++qt)
      ss += kq[qt][0]*kq[qt][0] + kq[qt][1]*kq[qt][1] + kq[qt][2]*kq[qt][2] + kq[qt][3]*kq[qt][3];
    #pragma unroll
    for (int m = 1; m < 16; m <<= 1) ss += __shfl_xor(ss, m);  // row spans 16 lanes
    float sc_ = 1.0f / fmaxf(sqrtf(ss), 1e-12f);
    #pragma unroll
    for (int qt = 0; qt < 4; ++qt) {
      int c = qt * 64 + lo * 4 + hi;
      u32x2 ko = xpose4(pack2(kq[qt][0] * sc_, kq[qt][1] * sc_),
                        pack2(kq[qt][2] * sc_, kq[qt][3] * sc_), hi);
      *(u32x2*)&KL[bufi][sidx32(c, m0)] = ko;
      u32x2 vo = xpose4(pack2(vq[qt][0], vq[qt][1]),
                        pack2(vq[qt][2], vq[qt][3]), hi);
      *(u32x2*)&VL[bufi][sidx32(c, m0)] = vo;
    }
  };
  auto MF = [&](const u16* KB, const u16* VB) {
    int acol = hi * 8;
    int r0 = w * 32 + lo, r1 = w * 32 + 16 + lo;
    short8 a0 = *(const short8*)&KB[(r0 * 32 + acol) ^ (((r0 >> 1) & 7) << 3)];
    short8 a1 = *(const short8*)&KB[(r1 * 32 + acol) ^ (((r1 >> 1) & 7) << 3)];
    #pragma unroll
    for (int dt = 0; dt < 16; ++dt) {
      int drow = dt * 16 + lo;
      short8 bb = *(const short8*)&VB[(drow * 32 + acol) ^ (((drow >> 1) & 7) << 3)];
      acc[0][dt] = __builtin_amdgcn_mfma_f32_16x16x32_bf16(bb, a0, acc[0][dt], 0, 0, 0);
      acc[1][dt] = __builtin_amdgcn_mfma_f32_16x16x32_bf16(bb, a1, acc[1][dt], 0, 0, 0);
    }
  };

  // ---- 2-deep pipeline over 32-row subtiles (nsc = KC/32 >= 4) ----
  int nsc = KC >> 5;
  LOADS(0, kqA, vqA);
  PIN();
  LOADS(1, kqB, vqB);
  PIN();
  STORE(0, kqA, vqA);
  BARRIER();
  for (int i = 0; i < nsc; i += 2) {
    if (i + 2 < nsc) { LOADS(i + 2, kqA, vqA); PIN(); }
    MF(KL[0], VL[0]);
    if (i + 1 < nsc) {
      STORE(1, kqB, vqB);
      BARRIER();
      if (i + 3 < nsc) { LOADS(i + 3, kqB, vqB); PIN(); }
      MF(KL[1], VL[1]);
      if (i + 2 < nsc) {
        STORE(0, kqA, vqA);
        BARRIER();
      }
    }
  }

  // epilogue: bf16 partial [s][b][256 d][256 c] (proven R7 form)
  size_t base = ((size_t)(s * NB + b)) << 16;
  #pragma unroll
  for (int i = 0; i < 2; i++) {
    int cc = w * 32 + i * 16 + lo;
    #pragma unroll
    for (int dt = 0; dt < 16; ++dt) {
      int dd = dt * 16 + hi * 4;
      #pragma unroll
      for (int r = 0; r < 4; r++)
        partial[base + (size_t)(dd + r) * 256 + cc] = f2bf(acc[i][dt][r]);
    }
  }
}

// ---------------- K2: elementwise reduce partials, scale 1/N, write kvT[d][c] bf16 ----------------
__global__ __launch_bounds__(256) void red_kernel(const u16* __restrict__ partial,
                                                  u16* __restrict__ kvT, int splits) {
  int j = blockIdx.x * 256 + threadIdx.x;   // 0..65535
  int b = j >> 13;
  int e0 = (j & 8191) * 8;
  size_t off = ((size_t)b << 16) + e0;
  const float inv = 1.0f / 4096.0f;
  float sum[8] = {0.f, 0.f, 0.f, 0.f, 0.f, 0.f, 0.f, 0.f};
  for (int s = 0; s < splits; ++s) {
    u16x8 p = *(const u16x8*)&partial[(((size_t)s * NB) << 16) + off];
    #pragma unroll
    for (int x = 0; x < 8; ++x) sum[x] += bf2f(p[x]);
  }
  u16x8 o;
  #pragma unroll
  for (int x = 0; x < 8; ++x) o[x] = f2bf(sum[x] * inv);
  *(u16x8*)&kvT[off] = o;
}

// ---------------- K3: out = normalize(q) @ kv (unchanged, proven) ----------------
__global__ __launch_bounds__(512) void ctx_kernel(const float* __restrict__ query,
                                                  const u16* __restrict__ kvT,
                                                  float* __restrict__ out) {
  __shared__ __align__(16) u16 qn[2][16 * 256];
  int t = threadIdx.x;
  int b = blockIdx.y;
  int tile0 = blockIdx.x * 4;
  int w = t >> 6, lane = t & 63, lo = lane & 15, hi = lane >> 4;
  int row = t >> 5, l32 = t & 31;
  const float* qbase = query + (size_t)b * NN * CDIM + (size_t)row * CDIM + l32 * 8;

  const float* qr0 = qbase + (size_t)(tile0 * 16) * CDIM;
  v4f x0 = *(const v4f*)qr0;
  v4f x1 = *(const v4f*)(qr0 + 4);

  const u16* kvb = kvT + ((size_t)b << 16);
  short8 Bf[2][8];
  #pragma unroll
  for (int i = 0; i < 2; i++) {
    int dr = (2 * w + i) * 16 + lo;
    #pragma unroll
    for (int kc = 0; kc < 8; kc++)
      Bf[i][kc] = *(const short8*)&kvb[(size_t)dr * 256 + kc * 32 + 8 * hi];
  }

  {
    float ss = x0[0]*x0[0] + x0[1]*x0[1] + x0[2]*x0[2] + x0[3]*x0[3]
             + x1[0]*x1[0] + x1[1]*x1[1] + x1[2]*x1[2] + x1[3]*x1[3];
    #pragma unroll
    for (int m = 1; m < 32; m <<= 1) ss += __shfl_xor(ss, m);
    float sc = 1.0f / fmaxf(sqrtf(ss), 1e-12f);
    u16x8 qb;
    qb[0] = f2bf(x0[0] * sc); qb[1] = f2bf(x0[1] * sc);
    qb[2] = f2bf(x0[2] * sc); qb[3] = f2bf(x0[3] * sc);
    qb[4] = f2bf(x1[0] * sc); qb[5] = f2bf(x1[1] * sc);
    qb[6] = f2bf(x1[2] * sc); qb[7] = f2bf(x1[3] * sc);
    *(u16x8*)&qn[0][(row * 256 + l32 * 8) ^ ((row & 7) << 3)] = qb;
  }

  int cur = 0;
  #pragma unroll
  for (int nt = 0; nt < 4; ++nt) {
    v4f p0, p1;
    if (nt < 3) {
      const float* qr = qbase + (size_t)((tile0 + nt + 1) * 16) * CDIM;
      p0 = *(const v4f*)qr;
      p1 = *(const v4f*)(qr + 4);
    }
    __syncthreads();
    short8 Af[8];
    #pragma unroll
    for (int kc = 0; kc < 8; kc++)
      Af[kc] = *(const short8*)&qn[cur][(lo * 256 + kc * 32 + 8 * hi) ^ ((lo & 7) << 3)];
    v4f acc0 = (v4f){0.f, 0.f, 0.f, 0.f};
    v4f acc1 = (v4f){0.f, 0.f, 0.f, 0.f};
    #pragma unroll
    for (int kc = 0; kc < 8; kc++) {
      acc0 = __builtin_amdgcn_mfma_f32_16x16x32_bf16(Af[kc], Bf[0][kc], acc0, 0, 0, 0);
      acc1 = __builtin_amdgcn_mfma_f32_16x16x32_bf16(Af[kc], Bf[1][kc], acc1, 0, 0, 0);
    }
    int n0 = (tile0 + nt) * 16;
    #pragma unroll
    for (int r = 0; r < 4; r++) {
      size_t ro = (size_t)(b * NN + n0 + 4 * hi + r) * CDIM;
      out[ro + (2 * w) * 16 + lo] = acc0[r];
      out[ro + (2 * w + 1) * 16 + lo] = acc1[r];
    }
    if (nt < 3) {
      float ss = p0[0]*p0[0] + p0[1]*p0[1] + p0[2]*p0[2] + p0[3]*p0[3]
               + p1[0]*p1[0] + p1[1]*p1[1] + p1[2]*p1[2] + p1[3]*p1[3];
      #pragma unroll
      for (int m = 1; m < 32; m <<= 1) ss += __shfl_xor(ss, m);
      float sc = 1.0f / fmaxf(sqrtf(ss), 1e-12f);
      u16x8 qb;
      qb[0] = f2bf(p0[0] * sc); qb[1] = f2bf(p0[1] * sc);
      qb[2] = f2bf(p0[2] * sc); qb[3] = f2bf(p0[3] * sc);
      qb[4] = f2bf(p1[0] * sc); qb[5] = f2bf(p1[1] * sc);
      qb[6] = f2bf(p1[2] * sc); qb[7] = f2bf(p1[3] * sc);
      *(u16x8*)&qn[cur ^ 1][(row * 256 + l32 * 8) ^ ((row & 7) << 3)] = qb;
      cur ^= 1;
    }
  }
}

extern "C" void kernel_launch(void* const* d_in, const int* in_sizes, int n_in,
                              void* d_out, int out_size, void* d_ws, size_t ws_size,
                              hipStream_t stream) {
  const float* q = (const float*)d_in[0];
  const float* k = (const float*)d_in[1];
  const float* v = (const float*)d_in[2];
  float* out = (float*)d_out;

  // ws layout: [partial: splits*8*256*256 bf16][kvT: 8*256*256 bf16]
  int splits = 32;
  while (splits > 2) {
    size_t need = ((size_t)splits + 1ull) * 1048576ull;
    if (need <= ws_size) break;
    splits >>= 1;
  }
  u16* partial = (u16*)d_ws;
  u16* kvT = (u16*)((char*)d_ws + (size_t)splits * 1048576ull);

  kv_kernel<<<dim3(splits, NB), dim3(512), 0, stream>>>(k, v, partial, MM / splits);
  red_kernel<<<dim3(256), dim3(256), 0, stream>>>(partial, kvT, splits);
  ctx_kernel<<<dim3(64, NB), dim3(512), 0, stream>>>(q, kvT, out);
}